// Round 8
// baseline (46.514 us; speedup 1.0000x reference)
//
#include <hip/hip_runtime.h>
#include <hip/hip_bf16.h>
#include <math.h>

#define TAU 0.75f

typedef _Float16 half8 __attribute__((ext_vector_type(8)));
typedef float    f32x4 __attribute__((ext_vector_type(4)));

// LDS-only barrier: orders ds ops, does NOT drain vmcnt (global ops in flight).
#define LDS_BARRIER() do {                                   \
    asm volatile("s_waitcnt lgkmcnt(0)" ::: "memory");       \
    __builtin_amdgcn_s_barrier();                            \
    asm volatile("" ::: "memory");                           \
} while (0)

// ws layout (float offsets)
#define WS_Q     0      // q[448]
#define WS_NORM2 448    // base ||W||^2
#define WS_SCALE 449    // 1/norm
#define WS_V01   450    // v0, v1
#define WS_I01   452    // i0, i1 (ints)
#define WS_WQ    456    // blended w-scales [192]
#define WS_FSC   648    // f scale [128]
#define WS_BADD  776    // f*bias*b [128]
#define WS_OW    904    // old_w [448]
#define WS_WF16  1352   // f16 fused conv weights [3][128][64] (16B aligned)

// ---------------------------------------------------------------------------
// K1: blocks 0..63 -> chunk c: rep row + 7 q entries. block 64 -> ||W||^2.
// ---------------------------------------------------------------------------
__global__ __launch_bounds__(256) void k1_rep_q(
    const float* __restrict__ grads, const float* __restrict__ ctrl_w,
    const float* __restrict__ ctrl_b,
    const float* __restrict__ cw_w, const float* __restrict__ cw_b,
    const float* __restrict__ cb_w, const float* __restrict__ cb_b,
    const float* __restrict__ cf_w, const float* __restrict__ cf_b,
    const float* __restrict__ W, float* __restrict__ ws)
{
    const int t = threadIdx.x;
    if (blockIdx.x == 64) {
        __shared__ float red[256];
        float ss = 0.f;
        for (int e = t; e < 3584; e += 256) {
            const float4 w4 = ((const float4*)W)[e];
            ss += w4.x * w4.x + w4.y * w4.y + w4.z * w4.z + w4.w * w4.w;
        }
        red[t] = ss; __syncthreads();
        for (int s = 128; s > 0; s >>= 1) { if (t < s) red[t] += red[t + s]; __syncthreads(); }
        if (t == 0) ws[WS_NORM2] = red[0];
        return;
    }
    const int c = blockIdx.x;
    __shared__ float gS[384];
    __shared__ float repS[64];
    if (t < 96) ((float4*)gS)[t] = ((const float4*)(grads + c * 384))[t];
    __syncthreads();
    {
        const int h = t >> 2, sub = t & 3;
        const float4* wa = (const float4*)(ctrl_w + h * 384) + sub * 24;
        const float4* ga = (const float4*)gS + sub * 24;
        float dot = 0.f;
        #pragma unroll
        for (int d = 0; d < 24; d++) {
            const float4 a = ga[d], b = wa[d];
            dot += a.x * b.x + a.y * b.y + a.z * b.z + a.w * b.w;
        }
        dot += __shfl_xor(dot, 1);
        dot += __shfl_xor(dot, 2);
        if (sub == 0) {
            const float z = dot + ctrl_b[h];
            repS[h] = z / (1.f + expf(-z));
        }
    }
    __syncthreads();
    if (t < 7) {
        const float* wv; float bias; int e;
        if (t < 3)      { wv = cw_w + t * 64;       bias = cw_b[t];     e = 3 * c + t; }
        else if (t < 5) { const int j = t - 3; wv = cb_w + j * 64; bias = cb_b[j]; e = 192 + 2 * c + j; }
        else            { const int j = t - 5; wv = cf_w + j * 64; bias = cf_b[j]; e = 320 + 2 * c + j; }
        float dot = 0.f;
        #pragma unroll 8
        for (int h = 0; h < 64; h++) dot += repS[h] * wv[h];
        ws[WS_Q + e] = dot + bias;
    }
}

// ---------------------------------------------------------------------------
// K2: single block. Scores -> softmax/top2 -> fused old_w + norm correction
// -> scale -> blended scales (wq, fsc, badd) -> ws.
// ---------------------------------------------------------------------------
__global__ __launch_bounds__(256) void k2_small(
    const float* __restrict__ W, const float* __restrict__ bias_param,
    const int* __restrict__ trigger, float* __restrict__ ws)
{
    __shared__ float qS[448], owS[448], sS[32], sW[4][32], red[256];
    __shared__ int   idxS[2];
    __shared__ float vS[2];
    const int t = threadIdx.x;
    const int wv = t >> 6, lane = t & 63;
    const int trig = trigger[0];

    for (int e = t; e < 448; e += 256) qS[e] = ws[WS_Q + e];
    __syncthreads();

    {
        const int m = lane & 31, half = lane >> 5;
        float s = 0.f;
        const int base = wv * 112;
        #pragma unroll 4
        for (int it = 0; it < 56; it++) {
            const int d = base + it * 2 + half;
            s += qS[d] * W[d * 32 + m];
        }
        s += __shfl_xor(s, 32);
        if (lane < 32) sW[wv][lane] = s;
    }
    __syncthreads();
    if (t < 32) sS[t] = 2.f * (sW[0][t] + sW[1][t] + sW[2][t] + sW[3][t]);
    __syncthreads();
    if (t == 0) {
        float mx = sS[0];
        for (int m = 1; m < 32; m++) mx = fmaxf(mx, sS[m]);
        float sum = 0.f; float att[32];
        for (int m = 0; m < 32; m++) { att[m] = expf(sS[m] - mx); sum += att[m]; }
        const float inv = 1.f / sum;
        int i0 = 0; float v0 = att[0];
        for (int m = 1; m < 32; m++) if (att[m] > v0) { v0 = att[m]; i0 = m; }
        int i1 = -1; float v1 = -1.f;
        for (int m = 0; m < 32; m++) { if (m == i0) continue; if (att[m] > v1) { v1 = att[m]; i1 = m; } }
        idxS[0] = i0; idxS[1] = i1; vS[0] = v0 * inv; vS[1] = v1 * inv;
    }
    __syncthreads();
    const int i0 = idxS[0], i1 = idxS[1];
    const float v0 = vS[0], v1 = vS[1];

    float corr = 0.f;
    for (int d = t; d < 448; d += 256) {
        const float w0 = W[d * 32 + i0], w1 = W[d * 32 + i1];
        const float ow = (trig == 1) ? (w0 * (float)i0 + w1 * (float)i1) : 0.f;
        owS[d] = ow;
        if (trig == 1) {
            const float n0 = TAU * w0 + 0.25f * ow * v0;
            const float n1 = TAU * w1 + 0.25f * ow * v1;
            corr += n0 * n0 - w0 * w0 + n1 * n1 - w1 * w1;
        }
    }
    red[t] = corr; __syncthreads();
    for (int s = 128; s > 0; s >>= 1) { if (t < s) red[t] += red[t + s]; __syncthreads(); }
    if (t == 0) {
        const float n = sqrtf(fmaxf(ws[WS_NORM2] + red[0], 0.f));
        ws[WS_SCALE] = 1.f / fmaxf(n, 1.f);
        ws[WS_V01] = v0; ws[WS_V01 + 1] = v1;
        ((int*)ws)[WS_I01] = i0; ((int*)ws)[WS_I01 + 1] = i1;
    }

    if (t < 192) ws[WS_WQ + t] = (trig == 1) ? (TAU * qS[t] + 0.25f * owS[t]) : qS[t];
    for (int o = t; o < 128; o += 256) {
        float bb = qS[192 + o], ff = qS[320 + o];
        if (trig == 1) {
            bb = TAU * bb + 0.25f * owS[192 + o];
            ff = TAU * ff + 0.25f * owS[320 + o];
        }
        ws[WS_FSC + o]  = ff;
        ws[WS_BADD + o] = ff * bias_param[o] * bb;
    }
    for (int d = t; d < 448; d += 256) ws[WS_OW + d] = owS[d];
}

// ---------------------------------------------------------------------------
// K3: 152 blocks: W_out[14336] + wf16[24576] from ws decisions.
// ---------------------------------------------------------------------------
__global__ __launch_bounds__(256) void k3_finalize(
    const float* __restrict__ W, const float* __restrict__ conv_weight,
    const int* __restrict__ trigger, const float* __restrict__ ws,
    float* __restrict__ W_out, _Float16* __restrict__ wf_out)
{
    const int g = blockIdx.x * 256 + threadIdx.x;
    const int trig = trigger[0];
    if (g < 14336) {
        const float wv = W[g];
        float wn = wv;
        if (trig == 1) {
            const int d = g >> 5, m = g & 31;
            const int i0 = ((const int*)ws)[WS_I01], i1 = ((const int*)ws)[WS_I01 + 1];
            if (m == i0)      wn = TAU * wv + 0.25f * ws[WS_OW + d] * ws[WS_V01];
            else if (m == i1) wn = TAU * wv + 0.25f * ws[WS_OW + d] * ws[WS_V01 + 1];
            wn *= ws[WS_SCALE];
        }
        W_out[g] = wn;
    } else {
        const int e2 = g - 14336;            // (o*64+i)*3+kk
        const int o   = e2 / 192;
        const int rem = e2 - o * 192;
        const int i   = rem / 3;
        const int kk  = rem - i * 3;
        wf_out[(kk * 128 + o) * 64 + i] = (_Float16)(conv_weight[e2] * ws[WS_WQ + rem]);
    }
}

// ---------------------------------------------------------------------------
// Conv via f16 MFMA, SWAPPED operands: A = x (rows = l), B = weights (cols = o).
// D layout: col = o = obase+of*16+(lane&15); row = l = lf*16+(lane>>4)*4+reg
// -> each thread stores float4 of 4 consecutive l per o (16 float4/thread,
//    was 64 scalar dwords). All loads identical to the unswapped version.
// Block: 128 o x (2 x 64 l) double-buffered; LDS-only barriers.
// Grid: 32 b * 32 l-groups = 1024 blocks (4/CU).
// ---------------------------------------------------------------------------
__global__ __launch_bounds__(256, 4) void conv_mfma(
    const float* __restrict__ x, const _Float16* __restrict__ wf,
    const float* __restrict__ fsc, const float* __restrict__ badd,
    float* __restrict__ out)
{
    __shared__ __align__(16) _Float16 xs[2][66 * 72];

    const int t    = threadIdx.x;
    const int wv   = t >> 6;
    const int lane = t & 63;
    const int lrow = lane & 15;
    const int lgrp = lane >> 4;
    const int b    = blockIdx.x >> 5;
    const int l0   = (blockIdx.x & 31) * 128;
    const int obase = wv * 32;

    const float* xb = x + (size_t)b * 64 * 4096;
    const int ci = t & 3;          // l-chunk of 16 within tile
    const int ir = t >> 2;         // row i, 0..63
    const int ei = t & 63;
    const int side = (t >> 6) & 1; // valid when t<128

    // weight fragments (now B-operand): wf[kk][o][i], o = obase+of*16+lrow
    half8 Wf[2][2][3];
    #pragma unroll
    for (int of = 0; of < 2; of++)
        #pragma unroll
        for (int ch = 0; ch < 2; ch++)
            #pragma unroll
            for (int kk = 0; kk < 3; kk++)
                Wf[of][ch][kk] = *(const half8*)(wf + ((kk * 128 + obase + of * 16 + lrow) * 64 + ch * 32 + lgrp * 8));

    float4 xr0[4]; float xe0 = 0.f;
    float4 xr1[4]; float xe1 = 0.f;

    // ---- load tile0
    {
        const int lb = l0;
        #pragma unroll
        for (int j = 0; j < 4; j++)
            xr0[j] = *(const float4*)(xb + (size_t)ir * 4096 + lb + ci * 16 + j * 4);
        if (t < 128) {
            const int l = side ? (lb + 64) : (lb - 1);
            if (l >= 0 && l < 4096) xe0 = xb[(size_t)ei * 4096 + l];
        }
    }
    // ---- write tile0 to LDS
    {
        _Float16* buf = xs[0];
        #pragma unroll
        for (int j = 0; j < 4; j++) {
            _Float16* p = buf + (ci * 16 + j * 4 + 1) * 72 + ir;
            p[0]   = (_Float16)xr0[j].x;
            p[72]  = (_Float16)xr0[j].y;
            p[144] = (_Float16)xr0[j].z;
            p[216] = (_Float16)xr0[j].w;
        }
        if (t < 128) buf[(side ? 65 : 0) * 72 + ei] = (_Float16)xe0;
    }
    // ---- issue tile1 loads (stay in flight across the LDS-only barrier)
    {
        const int lb = l0 + 64;
        #pragma unroll
        for (int j = 0; j < 4; j++)
            xr1[j] = *(const float4*)(xb + (size_t)ir * 4096 + lb + ci * 16 + j * 4);
        if (t < 128) {
            const int l = side ? (lb + 64) : (lb - 1);
            if (l >= 0 && l < 4096) xe1 = xb[(size_t)ei * 4096 + l];
        }
    }
    LDS_BARRIER();   // buf0 ready

    #pragma unroll
    for (int tile = 0; tile < 2; tile++) {
        const _Float16* buf = xs[tile];
        const int lb = l0 + tile * 64;

        f32x4 acc[2][4];
        #pragma unroll
        for (int of = 0; of < 2; of++)
            #pragma unroll
            for (int lf = 0; lf < 4; lf++) acc[of][lf] = (f32x4)0.f;

        #pragma unroll
        for (int ch = 0; ch < 2; ch++) {
            #pragma unroll
            for (int kk = 0; kk < 3; kk++) {
                half8 Xf[4];
                #pragma unroll
                for (int lf = 0; lf < 4; lf++)
                    Xf[lf] = *(const half8*)(buf + (lf * 16 + lrow + kk) * 72 + ch * 32 + lgrp * 8);
                #pragma unroll
                for (int of = 0; of < 2; of++)
                    #pragma unroll
                    for (int lf = 0; lf < 4; lf++)
                        acc[of][lf] = __builtin_amdgcn_mfma_f32_16x16x32_f16(Xf[lf], Wf[of][ch][kk], acc[of][lf], 0, 0, 0);
            }
        }

        // epilogue: o = obase + of*16 + lrow ; l = lb + lf*16 + lgrp*4 + {0..3}
        #pragma unroll
        for (int of = 0; of < 2; of++) {
            const int o = obase + of * 16 + lrow;
            const float fs = fsc[o], ba = badd[o];
            float* orow = out + ((size_t)(b * 128 + o)) * 4096 + lb + lgrp * 4;
            #pragma unroll
            for (int lf = 0; lf < 4; lf++) {
                float4 r;
                r.x = fs * acc[of][lf][0] + ba;
                r.y = fs * acc[of][lf][1] + ba;
                r.z = fs * acc[of][lf][2] + ba;
                r.w = fs * acc[of][lf][3] + ba;
                *(float4*)(orow + lf * 16) = r;
            }
        }

        if (tile == 0) {
            _Float16* buf1 = xs[1];
            #pragma unroll
            for (int j = 0; j < 4; j++) {
                _Float16* p = buf1 + (ci * 16 + j * 4 + 1) * 72 + ir;
                p[0]   = (_Float16)xr1[j].x;
                p[72]  = (_Float16)xr1[j].y;
                p[144] = (_Float16)xr1[j].z;
                p[216] = (_Float16)xr1[j].w;
            }
            if (t < 128) buf1[(side ? 65 : 0) * 72 + ei] = (_Float16)xe1;
            LDS_BARRIER();   // buf1 ready
        }
    }
}

extern "C" void kernel_launch(void* const* d_in, const int* in_sizes, int n_in,
                              void* d_out, int out_size, void* d_ws, size_t ws_size,
                              hipStream_t stream) {
    const float* x           = (const float*)d_in[0];
    const float* conv_weight = (const float*)d_in[1];
    const float* bias_param  = (const float*)d_in[2];
    const float* grads       = (const float*)d_in[3];
    const float* W           = (const float*)d_in[4];
    const float* ctrl_w      = (const float*)d_in[5];
    const float* ctrl_b      = (const float*)d_in[6];
    const float* cw_w        = (const float*)d_in[7];
    const float* cw_b        = (const float*)d_in[8];
    const float* cb_w        = (const float*)d_in[9];
    const float* cb_b        = (const float*)d_in[10];
    const float* cf_w        = (const float*)d_in[11];
    const float* cf_b        = (const float*)d_in[12];
    const int*   trigger     = (const int*)d_in[13];

    float* out   = (float*)d_out;
    float* W_out = out + (size_t)32 * 128 * 4096;   // 16777216
    float* ws    = (float*)d_ws;
    _Float16* wfp = (_Float16*)(ws + WS_WF16);
    float* fsc   = ws + WS_FSC;
    float* badd  = ws + WS_BADD;

    k1_rep_q<<<65, 256, 0, stream>>>(grads, ctrl_w, ctrl_b, cw_w, cw_b,
                                     cb_w, cb_b, cf_w, cf_b, W, ws);
    k2_small<<<1, 256, 0, stream>>>(W, bias_param, trigger, ws);
    k3_finalize<<<152, 256, 0, stream>>>(W, conv_weight, trigger, ws, W_out, wfp);
    conv_mfma<<<1024, 256, 0, stream>>>(x, wfp, fsc, badd, out);
}

// Round 9
// 41.771 us; speedup vs baseline: 1.1135x; 1.1135x over previous
//
#include <hip/hip_runtime.h>
#include <hip/hip_bf16.h>
#include <math.h>

#define TAU 0.75f

typedef _Float16 half8 __attribute__((ext_vector_type(8)));
typedef float    f32x4 __attribute__((ext_vector_type(4)));

// LDS-only barrier: orders ds ops, does NOT drain vmcnt (global ops in flight).
#define LDS_BARRIER() do {                                   \
    asm volatile("s_waitcnt lgkmcnt(0)" ::: "memory");       \
    __builtin_amdgcn_s_barrier();                            \
    asm volatile("" ::: "memory");                           \
} while (0)

// ws layout (float offsets)
#define WS_Q     0      // q[448]
#define WS_NORM2 448    // base ||W||^2
#define WS_SCALE 449    // 1/norm
#define WS_V01   450    // v0, v1
#define WS_I01   452    // i0, i1 (ints)
#define WS_WQ    456    // blended w-scales [192]
#define WS_FSC   648    // f scale [128]
#define WS_BADD  776    // f*bias*b [128]
#define WS_OW    904    // old_w [448]
#define WS_WF16  1352   // f16 fused conv weights [3][128][64] (16B aligned)

// ---------------------------------------------------------------------------
// K1: blocks 0..63 -> chunk c: rep row + 7 q entries. block 64 -> ||W||^2.
// ---------------------------------------------------------------------------
__global__ __launch_bounds__(256) void k1_rep_q(
    const float* __restrict__ grads, const float* __restrict__ ctrl_w,
    const float* __restrict__ ctrl_b,
    const float* __restrict__ cw_w, const float* __restrict__ cw_b,
    const float* __restrict__ cb_w, const float* __restrict__ cb_b,
    const float* __restrict__ cf_w, const float* __restrict__ cf_b,
    const float* __restrict__ W, float* __restrict__ ws)
{
    const int t = threadIdx.x;
    if (blockIdx.x == 64) {
        __shared__ float red[256];
        float ss = 0.f;
        for (int e = t; e < 3584; e += 256) {
            const float4 w4 = ((const float4*)W)[e];
            ss += w4.x * w4.x + w4.y * w4.y + w4.z * w4.z + w4.w * w4.w;
        }
        red[t] = ss; __syncthreads();
        for (int s = 128; s > 0; s >>= 1) { if (t < s) red[t] += red[t + s]; __syncthreads(); }
        if (t == 0) ws[WS_NORM2] = red[0];
        return;
    }
    const int c = blockIdx.x;
    __shared__ float gS[384];
    __shared__ float repS[64];
    if (t < 96) ((float4*)gS)[t] = ((const float4*)(grads + c * 384))[t];
    __syncthreads();
    {
        const int h = t >> 2, sub = t & 3;
        const float4* wa = (const float4*)(ctrl_w + h * 384) + sub * 24;
        const float4* ga = (const float4*)gS + sub * 24;
        float dot = 0.f;
        #pragma unroll
        for (int d = 0; d < 24; d++) {
            const float4 a = ga[d], b = wa[d];
            dot += a.x * b.x + a.y * b.y + a.z * b.z + a.w * b.w;
        }
        dot += __shfl_xor(dot, 1);
        dot += __shfl_xor(dot, 2);
        if (sub == 0) {
            const float z = dot + ctrl_b[h];
            repS[h] = z / (1.f + expf(-z));
        }
    }
    __syncthreads();
    if (t < 7) {
        const float* wv; float bias; int e;
        if (t < 3)      { wv = cw_w + t * 64;       bias = cw_b[t];     e = 3 * c + t; }
        else if (t < 5) { const int j = t - 3; wv = cb_w + j * 64; bias = cb_b[j]; e = 192 + 2 * c + j; }
        else            { const int j = t - 5; wv = cf_w + j * 64; bias = cf_b[j]; e = 320 + 2 * c + j; }
        float dot = 0.f;
        #pragma unroll 8
        for (int h = 0; h < 64; h++) dot += repS[h] * wv[h];
        ws[WS_Q + e] = dot + bias;
    }
}

// ---------------------------------------------------------------------------
// K2: single block. Scores -> softmax/top2 -> fused old_w + norm correction
// -> scale -> blended scales (wq, fsc, badd) -> ws.
// ---------------------------------------------------------------------------
__global__ __launch_bounds__(256) void k2_small(
    const float* __restrict__ W, const float* __restrict__ bias_param,
    const int* __restrict__ trigger, float* __restrict__ ws)
{
    __shared__ float qS[448], owS[448], sS[32], sW[4][32], red[256];
    __shared__ int   idxS[2];
    __shared__ float vS[2];
    const int t = threadIdx.x;
    const int wv = t >> 6, lane = t & 63;
    const int trig = trigger[0];

    for (int e = t; e < 448; e += 256) qS[e] = ws[WS_Q + e];
    __syncthreads();

    {
        const int m = lane & 31, half = lane >> 5;
        float s = 0.f;
        const int base = wv * 112;
        #pragma unroll 4
        for (int it = 0; it < 56; it++) {
            const int d = base + it * 2 + half;
            s += qS[d] * W[d * 32 + m];
        }
        s += __shfl_xor(s, 32);
        if (lane < 32) sW[wv][lane] = s;
    }
    __syncthreads();
    if (t < 32) sS[t] = 2.f * (sW[0][t] + sW[1][t] + sW[2][t] + sW[3][t]);
    __syncthreads();
    if (t == 0) {
        float mx = sS[0];
        for (int m = 1; m < 32; m++) mx = fmaxf(mx, sS[m]);
        float sum = 0.f; float att[32];
        for (int m = 0; m < 32; m++) { att[m] = expf(sS[m] - mx); sum += att[m]; }
        const float inv = 1.f / sum;
        int i0 = 0; float v0 = att[0];
        for (int m = 1; m < 32; m++) if (att[m] > v0) { v0 = att[m]; i0 = m; }
        int i1 = -1; float v1 = -1.f;
        for (int m = 0; m < 32; m++) { if (m == i0) continue; if (att[m] > v1) { v1 = att[m]; i1 = m; } }
        idxS[0] = i0; idxS[1] = i1; vS[0] = v0 * inv; vS[1] = v1 * inv;
    }
    __syncthreads();
    const int i0 = idxS[0], i1 = idxS[1];
    const float v0 = vS[0], v1 = vS[1];

    float corr = 0.f;
    for (int d = t; d < 448; d += 256) {
        const float w0 = W[d * 32 + i0], w1 = W[d * 32 + i1];
        const float ow = (trig == 1) ? (w0 * (float)i0 + w1 * (float)i1) : 0.f;
        owS[d] = ow;
        if (trig == 1) {
            const float n0 = TAU * w0 + 0.25f * ow * v0;
            const float n1 = TAU * w1 + 0.25f * ow * v1;
            corr += n0 * n0 - w0 * w0 + n1 * n1 - w1 * w1;
        }
    }
    red[t] = corr; __syncthreads();
    for (int s = 128; s > 0; s >>= 1) { if (t < s) red[t] += red[t + s]; __syncthreads(); }
    if (t == 0) {
        const float n = sqrtf(fmaxf(ws[WS_NORM2] + red[0], 0.f));
        ws[WS_SCALE] = 1.f / fmaxf(n, 1.f);
        ws[WS_V01] = v0; ws[WS_V01 + 1] = v1;
        ((int*)ws)[WS_I01] = i0; ((int*)ws)[WS_I01 + 1] = i1;
    }

    if (t < 192) ws[WS_WQ + t] = (trig == 1) ? (TAU * qS[t] + 0.25f * owS[t]) : qS[t];
    for (int o = t; o < 128; o += 256) {
        float bb = qS[192 + o], ff = qS[320 + o];
        if (trig == 1) {
            bb = TAU * bb + 0.25f * owS[192 + o];
            ff = TAU * ff + 0.25f * owS[320 + o];
        }
        ws[WS_FSC + o]  = ff;
        ws[WS_BADD + o] = ff * bias_param[o] * bb;
    }
    for (int d = t; d < 448; d += 256) ws[WS_OW + d] = owS[d];
}

// ---------------------------------------------------------------------------
// K3: 152 blocks: W_out[14336] + wf16[24576] from ws decisions.
// ---------------------------------------------------------------------------
__global__ __launch_bounds__(256) void k3_finalize(
    const float* __restrict__ W, const float* __restrict__ conv_weight,
    const int* __restrict__ trigger, const float* __restrict__ ws,
    float* __restrict__ W_out, _Float16* __restrict__ wf_out)
{
    const int g = blockIdx.x * 256 + threadIdx.x;
    const int trig = trigger[0];
    if (g < 14336) {
        const float wv = W[g];
        float wn = wv;
        if (trig == 1) {
            const int d = g >> 5, m = g & 31;
            const int i0 = ((const int*)ws)[WS_I01], i1 = ((const int*)ws)[WS_I01 + 1];
            if (m == i0)      wn = TAU * wv + 0.25f * ws[WS_OW + d] * ws[WS_V01];
            else if (m == i1) wn = TAU * wv + 0.25f * ws[WS_OW + d] * ws[WS_V01 + 1];
            wn *= ws[WS_SCALE];
        }
        W_out[g] = wn;
    } else {
        const int e2 = g - 14336;            // (o*64+i)*3+kk
        const int o   = e2 / 192;
        const int rem = e2 - o * 192;
        const int i   = rem / 3;
        const int kk  = rem - i * 3;
        wf_out[(kk * 128 + o) * 64 + i] = (_Float16)(conv_weight[e2] * ws[WS_WQ + rem]);
    }
}

// ---------------------------------------------------------------------------
// Conv via f16 MFMA, strip-pipelined. Block: 128 o x 256-l strip = 4 sub-tiles
// of 64 l, double-buffered LDS, LDS-only barriers. Pipeline per step:
// issue loads(t+2) -> compute+store(t) -> ds_write(t+1) -> barrier.
// Stores of t drain under loads/compute of t+1/t+2; A-frags loaded once/block.
// Grid: 32 b * 16 strips = 512 blocks (2/CU resident, continuous flow).
// ---------------------------------------------------------------------------
__global__ __launch_bounds__(256, 2) void conv_mfma(
    const float* __restrict__ x, const _Float16* __restrict__ wf,
    const float* __restrict__ fsc, const float* __restrict__ badd,
    float* __restrict__ out)
{
    __shared__ __align__(16) _Float16 xs[2][66 * 72];

    const int t     = threadIdx.x;
    const int wv    = t >> 6;
    const int lane  = t & 63;
    const int lrow  = lane & 15;
    const int lgrp  = lane >> 4;
    const int b     = blockIdx.x >> 4;        // 32 batches
    const int lbase = (blockIdx.x & 15) * 256; // strip start
    const int obase = wv * 32;

    const float* xb = x + (size_t)b * 64 * 4096;
    const int ci = t & 3;          // l-chunk of 16 within sub-tile
    const int ir = t >> 2;         // row i, 0..63
    const int ei = t & 63;
    const int side = (t >> 6) & 1; // valid when t<128

    // weight fragments (B-operand): wf[kk][o][i], o = obase+of*16+lrow
    half8 Wf[2][2][3];
    #pragma unroll
    for (int of = 0; of < 2; of++)
        #pragma unroll
        for (int ch = 0; ch < 2; ch++)
            #pragma unroll
            for (int kk = 0; kk < 3; kk++)
                Wf[of][ch][kk] = *(const half8*)(wf + ((kk * 128 + obase + of * 16 + lrow) * 64 + ch * 32 + lgrp * 8));

    // per-o epilogue constants (hoisted; constant across sub-tiles)
    float fs_[2], ba_[2];
    #pragma unroll
    for (int of = 0; of < 2; of++) {
        const int o = obase + of * 16 + lrow;
        fs_[of] = fsc[o]; ba_[of] = badd[o];
    }

    float4 xrA[4], xrB[4];
    float  xeA = 0.f, xeB = 0.f;

#define STAGE_LOAD(xr, xe, lb) do {                                          \
    _Pragma("unroll")                                                        \
    for (int j = 0; j < 4; j++)                                              \
        (xr)[j] = *(const float4*)(xb + (size_t)ir * 4096 + (lb) + ci * 16 + j * 4); \
    (xe) = 0.f;                                                              \
    if (t < 128) {                                                           \
        const int l_ = side ? ((lb) + 64) : ((lb) - 1);                      \
        if (l_ >= 0 && l_ < 4096) (xe) = xb[(size_t)ei * 4096 + l_];         \
    }                                                                        \
} while (0)

#define STAGE_WRITE(buf, xr, xe) do {                                        \
    _Pragma("unroll")                                                        \
    for (int j = 0; j < 4; j++) {                                            \
        _Float16* p_ = (buf) + (ci * 16 + j * 4 + 1) * 72 + ir;              \
        p_[0]   = (_Float16)(xr)[j].x;                                       \
        p_[72]  = (_Float16)(xr)[j].y;                                       \
        p_[144] = (_Float16)(xr)[j].z;                                       \
        p_[216] = (_Float16)(xr)[j].w;                                       \
    }                                                                        \
    if (t < 128) (buf)[(side ? 65 : 0) * 72 + ei] = (_Float16)(xe);          \
} while (0)

#define COMPUTE_STORE(buf, lb) do {                                          \
    f32x4 acc[2][4];                                                         \
    _Pragma("unroll")                                                        \
    for (int of = 0; of < 2; of++)                                           \
        _Pragma("unroll")                                                    \
        for (int lf = 0; lf < 4; lf++) acc[of][lf] = (f32x4)0.f;             \
    _Pragma("unroll")                                                        \
    for (int ch = 0; ch < 2; ch++) {                                         \
        _Pragma("unroll")                                                    \
        for (int kk = 0; kk < 3; kk++) {                                     \
            half8 Xf[4];                                                     \
            _Pragma("unroll")                                                \
            for (int lf = 0; lf < 4; lf++)                                   \
                Xf[lf] = *(const half8*)((buf) + (lf * 16 + lrow + kk) * 72 + ch * 32 + lgrp * 8); \
            _Pragma("unroll")                                                \
            for (int of = 0; of < 2; of++)                                   \
                _Pragma("unroll")                                            \
                for (int lf = 0; lf < 4; lf++)                               \
                    acc[of][lf] = __builtin_amdgcn_mfma_f32_16x16x32_f16(Xf[lf], Wf[of][ch][kk], acc[of][lf], 0, 0, 0); \
        }                                                                    \
    }                                                                        \
    _Pragma("unroll")                                                        \
    for (int of = 0; of < 2; of++) {                                         \
        const int o_ = obase + of * 16 + lrow;                               \
        float* orow_ = out + ((size_t)(b * 128 + o_)) * 4096 + (lb) + lgrp * 4; \
        _Pragma("unroll")                                                    \
        for (int lf = 0; lf < 4; lf++) {                                     \
            float4 r_;                                                       \
            r_.x = fs_[of] * acc[of][lf][0] + ba_[of];                       \
            r_.y = fs_[of] * acc[of][lf][1] + ba_[of];                       \
            r_.z = fs_[of] * acc[of][lf][2] + ba_[of];                       \
            r_.w = fs_[of] * acc[of][lf][3] + ba_[of];                       \
            *(float4*)(orow_ + lf * 16) = r_;                                \
        }                                                                    \
    }                                                                        \
} while (0)

    // ---- prologue: stage t0, issue t1
    STAGE_LOAD(xrA, xeA, lbase);
    STAGE_WRITE(xs[0], xrA, xeA);
    STAGE_LOAD(xrB, xeB, lbase + 64);
    LDS_BARRIER();                       // xs[0] ready; t1 loads in flight

    // ---- t=0
    STAGE_LOAD(xrA, xeA, lbase + 128);   // issue t2
    COMPUTE_STORE(xs[0], lbase);
    STAGE_WRITE(xs[1], xrB, xeB);        // waits only t1 loads
    LDS_BARRIER();

    // ---- t=1
    STAGE_LOAD(xrB, xeB, lbase + 192);   // issue t3
    COMPUTE_STORE(xs[1], lbase + 64);
    STAGE_WRITE(xs[0], xrA, xeA);
    LDS_BARRIER();

    // ---- t=2
    COMPUTE_STORE(xs[0], lbase + 128);
    STAGE_WRITE(xs[1], xrB, xeB);
    LDS_BARRIER();

    // ---- t=3
    COMPUTE_STORE(xs[1], lbase + 192);

#undef STAGE_LOAD
#undef STAGE_WRITE
#undef COMPUTE_STORE
}

extern "C" void kernel_launch(void* const* d_in, const int* in_sizes, int n_in,
                              void* d_out, int out_size, void* d_ws, size_t ws_size,
                              hipStream_t stream) {
    const float* x           = (const float*)d_in[0];
    const float* conv_weight = (const float*)d_in[1];
    const float* bias_param  = (const float*)d_in[2];
    const float* grads       = (const float*)d_in[3];
    const float* W           = (const float*)d_in[4];
    const float* ctrl_w      = (const float*)d_in[5];
    const float* ctrl_b      = (const float*)d_in[6];
    const float* cw_w        = (const float*)d_in[7];
    const float* cw_b        = (const float*)d_in[8];
    const float* cb_w        = (const float*)d_in[9];
    const float* cb_b        = (const float*)d_in[10];
    const float* cf_w        = (const float*)d_in[11];
    const float* cf_b        = (const float*)d_in[12];
    const int*   trigger     = (const int*)d_in[13];

    float* out   = (float*)d_out;
    float* W_out = out + (size_t)32 * 128 * 4096;   // 16777216
    float* ws    = (float*)d_ws;
    _Float16* wfp = (_Float16*)(ws + WS_WF16);
    float* fsc   = ws + WS_FSC;
    float* badd  = ws + WS_BADD;

    k1_rep_q<<<65, 256, 0, stream>>>(grads, ctrl_w, ctrl_b, cw_w, cw_b,
                                     cb_w, cb_b, cf_w, cf_b, W, ws);
    k2_small<<<1, 256, 0, stream>>>(W, bias_param, trigger, ws);
    k3_finalize<<<152, 256, 0, stream>>>(W, conv_weight, trigger, ws, W_out, wfp);
    conv_mfma<<<512, 256, 0, stream>>>(x, wfp, fsc, badd, out);
}